// Round 2
// baseline (284.011 us; speedup 1.0000x reference)
//
#include <hip/hip_runtime.h>

// Problem constants from the reference: B,C,H,W = 32,1,720,1280
constexpr int Bn = 32;
constexpr int Hn = 720;
constexpr int Wn = 1280;
constexpr int TOT = Bn * Hn;      // 23040 output rows
constexpr int GRID = 1280;        // 5 blocks/CU x 256 CU -> all resident, 18 rows/block
constexpr int BUF  = 3 * Wn;      // per-buffer floats: img row0 | img row1 | disp row

// Async global->LDS, 16B/lane (dest = wave-uniform base + lane*16, linear).
#define GLL(g, l) __builtin_amdgcn_global_load_lds(                         \
    (const __attribute__((address_space(1))) void*)(g),                     \
    (__attribute__((address_space(3))) void*)(l), 16, 0, 0)

#define WAITV(n) asm volatile("s_waitcnt vmcnt(" #n ")" ::: "memory")
#define MEMFENCE() asm volatile("" ::: "memory")

// Persistent double-buffered row-warp kernel.
// Per iteration (row t): buffer p holds {row y0c, row y1c, disp row t}.
// Prefetch of row t+GRID is in flight during compute of row t; steady-state
// wait is vmcnt(4) (= allow prev OUT store + 3 prefetch ops outstanding).
// Raw s_barrier + hand-counted vmcnt -- NO __syncthreads (compiler would
// drain vmcnt(0) before it and kill the pipeline).
__global__ __launch_bounds__(320) void warp_kernel(
    const float* __restrict__ img,
    const float* __restrict__ disp,
    float* __restrict__ out)
{
    __shared__ float srow[2 * BUF];   // 30720 B -> 5 blocks/CU (waves: 25/32)

    const int tid  = threadIdx.x;
    const int lane = tid & 63;
    const int wid  = tid >> 6;

    // ---- stage rows + disp for flat row t into buf (3 GLL per wave) ----
    auto stage = [&](float* buf, int t) {
        const int b = t / Hn;
        const int y = t - b * Hn;
        constexpr float sy = (float)Hn / (float)(Hn - 1);
        const float iy = fmaf((float)y, sy, -0.5f);   // = reference iy chain
        const int y0 = (int)floorf(iy);
        const int y1 = y0 + 1;
        const int y0c = min(max(y0, 0), Hn - 1);
        const int y1c = min(max(y1, 0), Hn - 1);
        const float* imb = img + b * (Hn * Wn);
        // img rows: 2560 floats as 10 chunks of 256; wave w owns chunks 2w,2w+1.
        // f = 512*w + 256*k; f<1280 -> row y0c at f, else row y1c at f-1280.
#pragma unroll
        for (int k = 0; k < 2; ++k) {
            const int f = (wid << 9) + (k << 8);
            const float* src = (f < Wn) ? (imb + y0c * Wn + f)
                                        : (imb + y1c * Wn + (f - Wn));
            GLL(src + (lane << 2), buf + f + (lane << 2));
        }
        // disp row: 1280 floats as 5 chunks of 256; wave w owns chunk w.
        const int g = (wid << 8);
        GLL(disp + t * Wn + g + (lane << 2), buf + 2 * Wn + g + (lane << 2));
    };

    // ---- compute one output row from staged buffer ----
    auto compute = [&](const float* buf, int t) {
        const int b = t / Hn;
        const int y = t - b * Hn;
        constexpr float sy = (float)Hn / (float)(Hn - 1);
        const float iy  = fmaf((float)y, sy, -0.5f);
        const float fy0 = floorf(iy);
        float wy1 = iy - fy0;
        float wy0 = 1.0f - wy1;
        const int y0 = (int)fy0;
        if (y0 < 0)       wy0 = 0.0f;   // y-validity folded into weights
        if (y0 + 1 >= Hn) wy1 = 0.0f;

        const float4 d4 = *reinterpret_cast<const float4*>(buf + 2 * Wn + (tid << 2));
        const float* r0 = buf;          // row y0c
        const float* r1 = buf + Wn;     // row y1c

        constexpr float sx = (float)Wn / (float)(Wn - 1);
        const float xf0 = (float)(tid << 2);
        const float dv[4] = {d4.x, d4.y, d4.z, d4.w};
        float res[4];
#pragma unroll
        for (int i = 0; i < 4; ++i) {
            // ix = (xf - d) * W/(W-1) - 0.5 (exact collapse of reference chain)
            const float ix  = fmaf(xf0 + (float)i - dv[i], sx, -0.5f);
            const float fx0 = floorf(ix);
            float wx1 = ix - fx0;
            float wx0 = 1.0f - wx1;
            const int x0 = (int)fx0;
            const int x1 = x0 + 1;
            wx0 = ((unsigned)x0 < (unsigned)Wn) ? wx0 : 0.0f;
            wx1 = ((unsigned)x1 < (unsigned)Wn) ? wx1 : 0.0f;
            const int xl0 = min(max(x0, 0), Wn - 1);
            const int xl1 = min(max(x1, 0), Wn - 1);

            const float v00 = r0[xl0];
            const float v01 = r0[xl1];
            const float v10 = r1[xl0];
            const float v11 = r1[xl1];

            const float t0v = v00 * wy0 + v10 * wy1;
            const float t1v = v01 * wy0 + v11 * wy1;
            res[i] = t0v * wx0 + t1v * wx1;
        }
        *reinterpret_cast<float4*>(out + t * Wn + (tid << 2)) =
            make_float4(res[0], res[1], res[2], res[3]);
    };

    // ---- persistent double-buffered main loop ----
    const int t0 = blockIdx.x;
    float* buf0 = srow;
    float* buf1 = srow + BUF;

    stage(buf0, t0);                       // prologue: current row
    if (t0 + GRID < TOT) stage(buf1, t0 + GRID);   // + lookahead row

    int p = 0;
    for (int t = t0; t < TOT; t += GRID, p ^= 1) {
        const bool hn = (t + GRID) < TOT;  // next prefetch outstanding?
        const bool hs = (t != t0);         // prev OUT store outstanding?
        // per-wave VMEM queue: [cur 3][(OUT prev)][(next 3)]; need cur 3 done
        if (hn) { if (hs) WAITV(4); else WAITV(3); }
        else    { if (hs) WAITV(1); else WAITV(0); }
        __builtin_amdgcn_s_barrier();      // all waves' staging landed
        MEMFENCE();
        float* buf = (p == 0) ? buf0 : buf1;
        compute(buf, t);
        MEMFENCE();
        __builtin_amdgcn_s_barrier();      // all waves done reading buf
        MEMFENCE();
        const int t2 = t + 2 * GRID;       // refill the buffer just consumed
        if (t2 < TOT) stage(buf, t2);
    }
}

extern "C" void kernel_launch(void* const* d_in, const int* in_sizes, int n_in,
                              void* d_out, int out_size, void* d_ws, size_t ws_size,
                              hipStream_t stream) {
    const float* img  = (const float*)d_in[0];   // right_img [32,1,720,1280] fp32
    const float* disp = (const float*)d_in[1];   // disp      [32,1,720,1280] fp32
    float* out = (float*)d_out;                  // [32,1,720,1280] fp32

    warp_kernel<<<GRID, 320, 0, stream>>>(img, disp, out);
}